// Round 2
// baseline (91.183 us; speedup 1.0000x reference)
//
#include <hip/hip_runtime.h>

// Conv2dLocal: spatially-varying depthwise 3x3 convolution.
// input:  [B, C, H, W]   fp32
// weight: [B, C*9, H, W] fp32 (tap t = i*3 + j, i=row offset, j=col offset)
// out:    [B, C, H, W]   fp32
// B=2, C=32, H=256, W=512 (powers of two -> shifts/masks)
//
// Memory-bound: 369 MB ideal traffic. Weight (302 MB) is streamed once ->
// non-temporal loads so L2/L3 keep the input planes (3x vertical reuse).
// 8 pixels/thread amortizes halo loads + index math.

constexpr int Bc = 2;
constexpr int Cc = 32;
constexpr int Hc = 256;
constexpr int Wc = 512;
constexpr int PIX = 8;            // pixels per thread
constexpr int WT  = Wc / PIX;     // 64 threads per row

typedef float vf4 __attribute__((ext_vector_type(4)));

__global__ __launch_bounds__(256) void conv2dlocal_kernel(
    const float* __restrict__ in,
    const float* __restrict__ wt,
    float* __restrict__ out)
{
    const int idx = blockIdx.x * blockDim.x + threadIdx.x;
    // idx = (bc*H + h)*WT + wv
    const int wv = idx & (WT - 1);
    const int t1 = idx >> 6;          // / WT
    const int h  = t1 & (Hc - 1);
    const int bc = t1 >> 8;           // b*C + c
    const int w0 = wv << 3;

    const float* ip = in + (size_t)bc * Hc * Wc;

    // 3 input rows x 10 columns (w0-1 .. w0+8), zero-padded at borders.
    // Input is cached (L2/L3) - plain loads.
    float v[3][10];
    #pragma unroll
    for (int r = 0; r < 3; ++r) {
        const int hh = h + r - 1;
        if (hh < 0 || hh >= Hc) {
            #pragma unroll
            for (int j = 0; j < 10; ++j) v[r][j] = 0.f;
        } else {
            const float* rp = ip + (size_t)hh * Wc + w0;
            const vf4 a = *reinterpret_cast<const vf4*>(rp);
            const vf4 b = *reinterpret_cast<const vf4*>(rp + 4);
            v[r][1] = a.x; v[r][2] = a.y; v[r][3] = a.z; v[r][4] = a.w;
            v[r][5] = b.x; v[r][6] = b.y; v[r][7] = b.z; v[r][8] = b.w;
            v[r][0] = (w0 > 0)        ? rp[-1] : 0.f;
            v[r][9] = (w0 + 8 < Wc)   ? rp[8]  : 0.f;
        }
    }

    // 9 weight planes, 2 coalesced float4 non-temporal reads each.
    float acc[8];
    #pragma unroll
    for (int k = 0; k < 8; ++k) acc[k] = 0.f;

    const float* wp = wt + ((size_t)bc * 9 * Hc + h) * Wc + w0;
    #pragma unroll
    for (int t = 0; t < 9; ++t) {
        const int r  = t / 3;
        const int cj = t % 3;
        const float* tp = wp + (size_t)t * Hc * Wc;
        const vf4 wa = __builtin_nontemporal_load(reinterpret_cast<const vf4*>(tp));
        const vf4 wb = __builtin_nontemporal_load(reinterpret_cast<const vf4*>(tp + 4));
        acc[0] = fmaf(wa.x, v[r][cj + 0], acc[0]);
        acc[1] = fmaf(wa.y, v[r][cj + 1], acc[1]);
        acc[2] = fmaf(wa.z, v[r][cj + 2], acc[2]);
        acc[3] = fmaf(wa.w, v[r][cj + 3], acc[3]);
        acc[4] = fmaf(wb.x, v[r][cj + 4], acc[4]);
        acc[5] = fmaf(wb.y, v[r][cj + 5], acc[5]);
        acc[6] = fmaf(wb.z, v[r][cj + 6], acc[6]);
        acc[7] = fmaf(wb.w, v[r][cj + 7], acc[7]);
    }

    float* op = out + (size_t)idx * PIX;
    vf4 o0; o0.x = acc[0]; o0.y = acc[1]; o0.z = acc[2]; o0.w = acc[3];
    vf4 o1; o1.x = acc[4]; o1.y = acc[5]; o1.z = acc[6]; o1.w = acc[7];
    __builtin_nontemporal_store(o0, reinterpret_cast<vf4*>(op));
    __builtin_nontemporal_store(o1, reinterpret_cast<vf4*>(op + 4));
}

extern "C" void kernel_launch(void* const* d_in, const int* in_sizes, int n_in,
                              void* d_out, int out_size, void* d_ws, size_t ws_size,
                              hipStream_t stream) {
    const float* in = (const float*)d_in[0];
    const float* wt = (const float*)d_in[1];
    float* out = (float*)d_out;

    const int total_threads = Bc * Cc * Hc * WT;   // 2*32*256*64 = 1,048,576
    const int block = 256;
    const int grid = total_threads / block;        // 4096
    conv2dlocal_kernel<<<grid, block, 0, stream>>>(in, wt, out);
}

// Round 3
// 66.166 us; speedup vs baseline: 1.3781x; 1.3781x over previous
//
#include <hip/hip_runtime.h>

// Conv2dLocal: spatially-varying depthwise 3x3 convolution.
// input:  [B, C, H, W]   fp32
// weight: [B, C*9, H, W] fp32 (tap t = i*3 + j, i=row offset, j=col offset)
// out:    [B, C, H, W]   fp32
// B=2, C=32, H=256, W=512 (powers of two -> shifts/masks)
//
// Memory-bound: ~369 MB ideal traffic, weight stream = 82% of it.
// 4 pixels/thread: each weight-load instruction is a fully-dense 1 KB/wave
// coalesced read, so non-temporal (evict-first) hints are safe — no
// second instruction ever needs the same cache line. nt on weight loads +
// output stores keeps L2/L3 for the input planes (3x vertical reuse).

constexpr int Bc = 2;
constexpr int Cc = 32;
constexpr int Hc = 256;
constexpr int Wc = 512;
constexpr int W4 = Wc / 4;  // 128 float4-threads per row

typedef float vf4 __attribute__((ext_vector_type(4)));

__global__ __launch_bounds__(256) void conv2dlocal_kernel(
    const float* __restrict__ in,
    const float* __restrict__ wt,
    float* __restrict__ out)
{
    const int idx = blockIdx.x * blockDim.x + threadIdx.x;
    // idx = (bc*H + h)*W4 + wv
    const int wv = idx & (W4 - 1);
    const int t1 = idx >> 7;          // / W4
    const int h  = t1 & (Hc - 1);
    const int bc = t1 >> 8;           // b*C + c
    const int w0 = wv << 2;

    const float* ip = in + (size_t)bc * Hc * Wc;

    // 3 input rows x 6 columns (w0-1 .. w0+4), zero-padded at borders.
    // Input has 3x vertical reuse -> plain (cached) loads.
    float v[3][6];
    #pragma unroll
    for (int r = 0; r < 3; ++r) {
        const int hh = h + r - 1;
        if (hh < 0 || hh >= Hc) {
            #pragma unroll
            for (int j = 0; j < 6; ++j) v[r][j] = 0.f;
        } else {
            const float* rp = ip + (size_t)hh * Wc + w0;
            const vf4 c4 = *reinterpret_cast<const vf4*>(rp);
            v[r][1] = c4.x; v[r][2] = c4.y; v[r][3] = c4.z; v[r][4] = c4.w;
            v[r][0] = (w0 > 0)      ? rp[-1] : 0.f;
            v[r][5] = (w0 + 4 < Wc) ? rp[4]  : 0.f;
        }
    }

    // 9 weight planes, each a fully-coalesced float4 non-temporal read.
    float acc0 = 0.f, acc1 = 0.f, acc2 = 0.f, acc3 = 0.f;
    const float* wp = wt + ((size_t)bc * 9 * Hc + h) * Wc + w0;
    #pragma unroll
    for (int t = 0; t < 9; ++t) {
        const int r  = t / 3;
        const int cj = t % 3;
        const vf4 w4 = __builtin_nontemporal_load(
            reinterpret_cast<const vf4*>(wp + (size_t)t * Hc * Wc));
        acc0 = fmaf(w4.x, v[r][cj + 0], acc0);
        acc1 = fmaf(w4.y, v[r][cj + 1], acc1);
        acc2 = fmaf(w4.z, v[r][cj + 2], acc2);
        acc3 = fmaf(w4.w, v[r][cj + 3], acc3);
    }

    vf4 o; o.x = acc0; o.y = acc1; o.z = acc2; o.w = acc3;
    __builtin_nontemporal_store(o, reinterpret_cast<vf4*>(out + (size_t)idx * 4));
}

extern "C" void kernel_launch(void* const* d_in, const int* in_sizes, int n_in,
                              void* d_out, int out_size, void* d_ws, size_t ws_size,
                              hipStream_t stream) {
    const float* in = (const float*)d_in[0];
    const float* wt = (const float*)d_in[1];
    float* out = (float*)d_out;

    const int total_threads = Bc * Cc * Hc * W4;   // 2*32*256*128 = 2,097,152
    const int block = 256;
    const int grid = total_threads / block;        // 8192
    conv2dlocal_kernel<<<grid, block, 0, stream>>>(in, wt, out);
}

// Round 4
// 62.646 us; speedup vs baseline: 1.4555x; 1.0562x over previous
//
#include <hip/hip_runtime.h>

// Conv2dLocal: spatially-varying depthwise 3x3 convolution.
// input:  [B, C, H, W]   fp32
// weight: [B, C*9, H, W] fp32 (tap t = i*3 + j, i=row offset, j=col offset)
// out:    [B, C, H, W]   fp32
// B=2, C=32, H=256, W=512 (powers of two -> shifts/masks)
//
// Memory-bound: ~369 MB ideal traffic, weight stream = 82% of it.
// - nt loads on weight (streamed once), nt stores on output.
// - 4 pixels/thread: every weight-load instruction is a dense 1 KB/wave
//   coalesced read (nt-safe, no partial-line refetch).
// - XCD-aware block swizzle: each block's 2 output rows share 2 input rows
//   with the neighboring block; default round-robin dispatch puts neighbors
//   on different XCDs (private L2s) -> input fetched from HBM ~2x. Swizzle
//   gives each XCD a contiguous row range so shared rows hit the same L2.

constexpr int Bc = 2;
constexpr int Cc = 32;
constexpr int Hc = 256;
constexpr int Wc = 512;
constexpr int W4 = Wc / 4;  // 128 float4-threads per row
constexpr int NXCD = 8;

typedef float vf4 __attribute__((ext_vector_type(4)));

__global__ __launch_bounds__(256) void conv2dlocal_kernel(
    const float* __restrict__ in,
    const float* __restrict__ wt,
    float* __restrict__ out)
{
    // Bijective XCD swizzle (gridDim.x = 8192, divisible by 8):
    // XCD k = bid%8 gets the contiguous work chunk [k*1024, (k+1)*1024).
    const int bid  = blockIdx.x;
    const int cpx  = gridDim.x >> 3;                 // chunk per XCD = 1024
    const int wb   = (bid & (NXCD - 1)) * cpx + (bid >> 3);

    const int idx = wb * blockDim.x + threadIdx.x;
    // idx = (bc*H + h)*W4 + wv
    const int wv = idx & (W4 - 1);
    const int t1 = idx >> 7;          // / W4
    const int h  = t1 & (Hc - 1);
    const int bc = t1 >> 8;           // b*C + c
    const int w0 = wv << 2;

    const float* ip = in + (size_t)bc * Hc * Wc;

    // 3 input rows x 6 columns (w0-1 .. w0+4), zero-padded at borders.
    // Input has vertical reuse -> plain (cached) loads.
    float v[3][6];
    #pragma unroll
    for (int r = 0; r < 3; ++r) {
        const int hh = h + r - 1;
        if (hh < 0 || hh >= Hc) {
            #pragma unroll
            for (int j = 0; j < 6; ++j) v[r][j] = 0.f;
        } else {
            const float* rp = ip + (size_t)hh * Wc + w0;
            const vf4 c4 = *reinterpret_cast<const vf4*>(rp);
            v[r][1] = c4.x; v[r][2] = c4.y; v[r][3] = c4.z; v[r][4] = c4.w;
            v[r][0] = (w0 > 0)      ? rp[-1] : 0.f;
            v[r][5] = (w0 + 4 < Wc) ? rp[4]  : 0.f;
        }
    }

    // 9 weight planes, each a fully-coalesced float4 non-temporal read.
    float acc0 = 0.f, acc1 = 0.f, acc2 = 0.f, acc3 = 0.f;
    const float* wp = wt + ((size_t)bc * 9 * Hc + h) * Wc + w0;
    #pragma unroll
    for (int t = 0; t < 9; ++t) {
        const int r  = t / 3;
        const int cj = t % 3;
        const vf4 w4 = __builtin_nontemporal_load(
            reinterpret_cast<const vf4*>(wp + (size_t)t * Hc * Wc));
        acc0 = fmaf(w4.x, v[r][cj + 0], acc0);
        acc1 = fmaf(w4.y, v[r][cj + 1], acc1);
        acc2 = fmaf(w4.z, v[r][cj + 2], acc2);
        acc3 = fmaf(w4.w, v[r][cj + 3], acc3);
    }

    vf4 o; o.x = acc0; o.y = acc1; o.z = acc2; o.w = acc3;
    __builtin_nontemporal_store(o, reinterpret_cast<vf4*>(out + (size_t)idx * 4));
}

extern "C" void kernel_launch(void* const* d_in, const int* in_sizes, int n_in,
                              void* d_out, int out_size, void* d_ws, size_t ws_size,
                              hipStream_t stream) {
    const float* in = (const float*)d_in[0];
    const float* wt = (const float*)d_in[1];
    float* out = (float*)d_out;

    const int total_threads = Bc * Cc * Hc * W4;   // 2*32*256*128 = 2,097,152
    const int block = 256;
    const int grid = total_threads / block;        // 8192 (divisible by 8)
    conv2dlocal_kernel<<<grid, block, 0, stream>>>(in, wt, out);
}